// Round 3
// baseline (209.556 us; speedup 1.0000x reference)
//
#include <hip/hip_runtime.h>

// YOLO-style loss on MI355X — round 7.
// pred:      [B, 8, 8, 8] f32   (B = 65536)
// label_rc:  [B, L, 2]    i32   (L = 16)
// label_box: [B, L, 3]    f32
// out:       [1] f32 = (coord + cond) / B
//
// R7: latency-hiding rewrite. R6 (~62 us inferred) was latency-bound:
// label loads issued late (900 cyc exposed per super), LDS staging
// write+drain+read on the critical path, and 2-super wave lifetimes (no
// steady state). R7:
//   - 4096 persistent waves (1024 blocks x 4), each owns a CONTIGUOUS
//     16-batch span = 4 supers; 4 blocks/CU resident, one generation.
//   - ping-pong register pipeline: pred (8x dwordx4) AND labels (int2 +
//     3 floats) for super i+1 issued before processing super i ->
//     dependent-load latency hidden under compute + other waves.
//   - responsible-cell gather = 2 global dwordx4 re-reads of the 32 B
//     cell. Those lines were streamed by THIS wave one super ago ->
//     L1/L2-hit (~200 cyc), issued early, off critical path. Deletes the
//     32 KB LDS staging entirely (LDS now 144 B -> occupancy VGPR-bound).
//   - obj-mask dedup unchanged: one ds_or_rtn_b32 per label on a
//     per-(wave,batch) LDS word; first setter owns the cell.
// Inputs (148 MiB) are LLC-resident across bench iterations (R5 counter:
// FETCH_SIZE 78 MB << 155 MB), so the floor is below the 25 us HBM bound.

static constexpr float LAMBDA_COORD = 5.0f;
static constexpr float LAMBDA_NOOBJ = 0.5f;
static constexpr float EPS_F = 1e-9f;

#define WAVES_PER_BLOCK 4
#define SUPER  4          // batches per super-iteration (one per 16-lane group)
#define NBLOCKS 1024

__device__ __forceinline__ float bbox_iou(float px, float py, float pr,
                                          float gx, float gy, float gr) {
    float l1 = px - pr, r1 = px + pr, t1 = py - pr, b1 = py + pr;
    float l2 = gx - gr, r2 = gx + gr, t2 = gy - gr, b2 = gy + gr;
    float iw = fmaxf(fminf(r1, r2) - fmaxf(l1, l2), 0.0f);
    float ih = fmaxf(fminf(b1, b2) - fmaxf(t1, t2), 0.0f);
    float inter = iw * ih;
    float a1 = (r1 - l1) * (b1 - t1);
    float a2 = (r2 - l2) * (b2 - t2);
    return inter / (a1 + a2 - inter + EPS_F);
}

// Per-super register state: 8 float4 of pred + this lane's label.
#define DECL_SUPER(S)                                                          \
    float4 S##_q0, S##_q1, S##_q2, S##_q3, S##_q4, S##_q5, S##_q6, S##_q7;     \
    int    S##_cell = 0, S##_ok = 0;                                           \
    float  S##_gx = 0.f, S##_gy = 0.f, S##_gr = 0.f;

// Issue all loads for super g (pred stream + this lane's label) into S.
#define LOAD_SUPER(S, g)                                                       \
    {                                                                          \
        const long bb_ = (long)(g) * SUPER;                                    \
        const float4* gp_ = (const float4*)(pred + bb_ * 512);                 \
        if (bb_ + SUPER <= (long)B) {          /* fast path: full super */     \
            S##_q0 = gp_[lane];        S##_q1 = gp_[lane + 64];                \
            S##_q2 = gp_[lane + 128];  S##_q3 = gp_[lane + 192];               \
            S##_q4 = gp_[lane + 256];  S##_q5 = gp_[lane + 320];               \
            S##_q6 = gp_[lane + 384];  S##_q7 = gp_[lane + 448];               \
        } else {                                                               \
            const float4 z_ = make_float4(0.f, 0.f, 0.f, 0.f);                 \
            S##_q0 = S##_q1 = S##_q2 = S##_q3 = z_;                            \
            S##_q4 = S##_q5 = S##_q6 = S##_q7 = z_;                            \
            if (bb_ + 0 < (long)B) { S##_q0 = gp_[lane];       S##_q1 = gp_[lane + 64];  } \
            if (bb_ + 1 < (long)B) { S##_q2 = gp_[lane + 128]; S##_q3 = gp_[lane + 192]; } \
            if (bb_ + 2 < (long)B) { S##_q4 = gp_[lane + 256]; S##_q5 = gp_[lane + 320]; } \
            if (bb_ + 3 < (long)B) { S##_q6 = gp_[lane + 384]; S##_q7 = gp_[lane + 448]; } \
        }                                                                      \
        const long bq_ = bb_ + grp;                                            \
        S##_ok = (bq_ < (long)B) && (lj < L);                                  \
        if (S##_ok) {                                                          \
            const int2 rc_ = *(const int2*)(label_rc + ((size_t)bq_ * L + lj) * 2); \
            S##_cell = rc_.x * 8 + rc_.y;       /* 0..63 */                    \
            const float* lb_ = label_box + ((size_t)bq_ * L + lj) * 3;         \
            S##_gx = lb_[0]; S##_gy = lb_[1]; S##_gr = lb_[2];                 \
        }                                                                      \
    }

// Process super g from S: noobj sum, L2-hot gather, dedup, per-label loss.
#define PROC_SUPER(S, g)                                                       \
    {                                                                          \
        noobj_acc += S##_q0.w * S##_q0.w + S##_q1.w * S##_q1.w                 \
                   + S##_q2.w * S##_q2.w + S##_q3.w * S##_q3.w                 \
                   + S##_q4.w * S##_q4.w + S##_q5.w * S##_q5.w                 \
                   + S##_q6.w * S##_q6.w + S##_q7.w * S##_q7.w;                \
        if (lane < SUPER * 2) my_mask[lane] = 0u;                              \
        asm volatile("s_waitcnt lgkmcnt(0)" ::: "memory");                     \
        if (S##_ok) {                                                          \
            const long bq_ = (long)(g) * SUPER + grp;                          \
            const float4* cp_ =                                                \
                (const float4*)(pred + (size_t)bq_ * 512 + (size_t)S##_cell * 8); \
            const float4 c0_ = cp_[0];          /* L1/L2 hit: streamed above */\
            const float4 c1_ = cp_[1];                                         \
            const unsigned bit_ = 1u << (S##_cell & 31);                       \
            const unsigned old_ =                                              \
                atomicOr(&my_mask[grp * 2 + (S##_cell >> 5)], bit_);           \
            const float p0 = c0_.x, p1 = c0_.y, p2 = c0_.z, p3 = c0_.w;        \
            const float p4 = c1_.x, p5 = c1_.y, p6 = c1_.z, p7 = c1_.w;        \
            const float iou1 = bbox_iou(p0, p1, p2, S##_gx, S##_gy, S##_gr);   \
            const float iou2 = bbox_iou(p4, p5, p6, S##_gx, S##_gy, S##_gr);   \
            const bool  sw_ = iou2 > iou1;                                     \
            const float cx = sw_ ? p4 : p0;                                    \
            const float cy = sw_ ? p5 : p1;                                    \
            const float cr = sw_ ? p6 : p2;                                    \
            const float conf    = sw_ ? p7 : p3;                               \
            const float un_conf = sw_ ? p3 : p7;                               \
            const float bigger  = sw_ ? iou2 : iou1;                           \
            const float smaller = sw_ ? iou1 : iou2;                           \
            const float dx = cx - S##_gx, dy = cy - S##_gy, dr = cr - S##_gr;  \
            main_acc += LAMBDA_COORD * (dx * dx + dy * dy + dr * dr);          \
            const float d1 = bigger - conf;                                    \
            main_acc += d1 * d1;                                               \
            const float d2 = smaller - un_conf;                                \
            noobj_acc += d2 * d2;                                              \
            if ((old_ & bit_) == 0u)     /* owner: subtract labeled cell */    \
                noobj_acc -= (p3 * p3 + p7 * p7);                              \
        }                                                                      \
    }

__global__ __launch_bounds__(256, 4) void yolo_loss_kernel(
    const float* __restrict__ pred,
    const int*   __restrict__ label_rc,
    const float* __restrict__ label_box,
    float* __restrict__ partials,
    int B, int L)
{
    __shared__ unsigned cmask[WAVES_PER_BLOCK][SUPER * 2];   // 128 B
    __shared__ float    wsum[WAVES_PER_BLOCK];

    const int tid  = threadIdx.x;
    const int lane = tid & 63;
    const int wv   = tid >> 6;
    const int grp  = lane >> 4;     // which batch of the super
    const int lj   = lane & 15;     // label index within that batch

    unsigned* my_mask = cmask[wv];

    const long waves_tot = (long)gridDim.x * WAVES_PER_BLOCK;
    const long wgid      = (long)blockIdx.x * WAVES_PER_BLOCK + wv;
    const long nsup      = ((long)B + SUPER - 1) / SUPER;
    const long spw       = (nsup + waves_tot - 1) / waves_tot;
    const long g_begin   = wgid * spw;
    const long g_end     = (g_begin + spw < nsup) ? (g_begin + spw) : nsup;

    float main_acc  = 0.0f;  // lambda_coord * coord + d1^2
    float noobj_acc = 0.0f;  // sum w^2 - owner(p3^2+p7^2) + d2^2 (x lambda at end)

    DECL_SUPER(A)
    DECL_SUPER(B)

    long g = g_begin;
    if (g < g_end) {
        LOAD_SUPER(A, g);
        while (true) {
            if (g + 1 < g_end) LOAD_SUPER(B, g + 1);   // prefetch next
            PROC_SUPER(A, g);
            ++g; if (g >= g_end) break;
            if (g + 1 < g_end) LOAD_SUPER(A, g + 1);   // prefetch next-next
            PROC_SUPER(B, g);
            ++g; if (g >= g_end) break;
        }
    }

    // ---- wave + block reduction -> one partial per block ----
    float acc = main_acc + LAMBDA_NOOBJ * noobj_acc;
    #pragma unroll
    for (int off = 32; off > 0; off >>= 1)
        acc += __shfl_xor(acc, off);
    if (lane == 0) wsum[wv] = acc;
    __syncthreads();
    if (tid == 0)
        partials[blockIdx.x] = wsum[0] + wsum[1] + wsum[2] + wsum[3];
}

__global__ __launch_bounds__(256) void reduce_kernel(
    const float* __restrict__ partials, float* __restrict__ out,
    int n, float invB)
{
    float s = 0.0f;
    for (int i = threadIdx.x; i < n; i += 256)
        s += partials[i];
    #pragma unroll
    for (int off = 32; off > 0; off >>= 1)
        s += __shfl_xor(s, off);

    __shared__ float wsum[4];
    const int lane = threadIdx.x & 63, w = threadIdx.x >> 6;
    if (lane == 0) wsum[w] = s;
    __syncthreads();
    if (threadIdx.x == 0)
        out[0] = (wsum[0] + wsum[1] + wsum[2] + wsum[3]) * invB;
}

extern "C" void kernel_launch(void* const* d_in, const int* in_sizes, int n_in,
                              void* d_out, int out_size, void* d_ws, size_t ws_size,
                              hipStream_t stream) {
    const float* pred      = (const float*)d_in[0];
    const int*   label_rc  = (const int*)d_in[1];
    const float* label_box = (const float*)d_in[2];
    float*       out       = (float*)d_out;
    float*       partials  = (float*)d_ws;

    const int B = in_sizes[0] / 512;          // G*G*C = 8*8*8
    const int L = in_sizes[1] / (B * 2);      // labels per batch (16)
    const float invB = 1.0f / (float)B;

    yolo_loss_kernel<<<NBLOCKS, 256, 0, stream>>>(
        pred, label_rc, label_box, partials, B, L);

    reduce_kernel<<<1, 256, 0, stream>>>(partials, out, NBLOCKS, invB);
}

// Round 4
// 206.701 us; speedup vs baseline: 1.0138x; 1.0138x over previous
//
#include <hip/hip_runtime.h>

// YOLO-style loss on MI355X — round 8.
// pred:      [B, 8, 8, 8] f32   (B = 65536)
// label_rc:  [B, L, 2]    i32   (L = 16)
// label_box: [B, L, 3]    f32
// out:       [1] f32 = (coord + cond) / B
//
// R8: fix R7's vmcnt-ordering bug. vmcnt retires IN ISSUE ORDER, so R7's
// "issue next prefetch, then issue gather, then use gather" forced an
// effective vmcnt(0) at every super -> one full memory round trip exposed
// per super (~62 us). R8 reorders issuance so every wait is a queue PREFIX:
//   per super i (steady state, queue oldest->newest shown in brackets):
//     1. wait labels(i)           [leaves pred(i) in flight]
//        compute cell(i), reset dedup mask, ISSUE gather(i)
//     2. issue labels(i+1) THEN pred(i+1)   (labels older -> cheap wait next iter)
//     3. noobj(i): wait pred(i)   [leaves gather(i)+labels(i+1)+pred(i+1)]
//     4. IoU(i):  wait gather(i)  [leaves labels(i+1)+pred(i+1) in flight]
// The bulk pred stream never drains -> memory floor (~76-148 MB HBM-side
// after the 512 MiB harness fills partially evict LLC) instead of serialized
// latency. Gather races its own super's stream fetch; L2 MSHRs merge it.
// Dedup unchanged: one ds_or_rtn per label on a per-(wave,super-batch) LDS
// word; same-wave DS ops are in-order, so no lgkmcnt asm needed.

static constexpr float LAMBDA_COORD = 5.0f;
static constexpr float LAMBDA_NOOBJ = 0.5f;
static constexpr float EPS_F = 1e-9f;

#define WAVES_PER_BLOCK 4
#define SUPER   4         // batches per super-iteration (one per 16-lane group)
#define NBLOCKS 1024      // 4096 waves; 4 blocks/CU resident; 4 supers/wave

__device__ __forceinline__ float bbox_iou(float px, float py, float pr,
                                          float gx, float gy, float gr) {
    float l1 = px - pr, r1 = px + pr, t1 = py - pr, b1 = py + pr;
    float l2 = gx - gr, r2 = gx + gr, t2 = gy - gr, b2 = gy + gr;
    float iw = fmaxf(fminf(r1, r2) - fmaxf(l1, l2), 0.0f);
    float ih = fmaxf(fminf(b1, b2) - fmaxf(t1, t2), 0.0f);
    float inter = iw * ih;
    float a1 = (r1 - l1) * (b1 - t1);
    float a2 = (r2 - l2) * (b2 - t2);
    return inter / (a1 + a2 - inter + EPS_F);
}

// Per-super register state.
#define DECL_SUPER(S)                                                          \
    float4 S##_q0, S##_q1, S##_q2, S##_q3, S##_q4, S##_q5, S##_q6, S##_q7;     \
    int2   S##_rc   = make_int2(0, 0);                                         \
    float  S##_gx = 0.f, S##_gy = 0.f, S##_gr = 0.f;                           \
    int    S##_ok = 0, S##_cell = 0;                                           \
    float4 S##_c0 = make_float4(0.f, 0.f, 0.f, 0.f);                           \
    float4 S##_c1 = make_float4(0.f, 0.f, 0.f, 0.f);

// Issue super g's loads: labels FIRST (so next iteration's label wait is a
// short queue prefix), then the 8-dwordx4 pred stream. No use of results here.
#define LOAD_SUPER(S, g)                                                       \
    {                                                                          \
        const long bb_ = (long)(g) * SUPER;                                    \
        const long bq_ = bb_ + grp;                                            \
        S##_ok = (bq_ < (long)B) && (lj < L);                                  \
        if (S##_ok) {                                                          \
            S##_rc = *(const int2*)(label_rc + ((size_t)bq_ * L + lj) * 2);    \
            const float* lb_ = label_box + ((size_t)bq_ * L + lj) * 3;         \
            S##_gx = lb_[0]; S##_gy = lb_[1]; S##_gr = lb_[2];                 \
        }                                                                      \
        const float4* gp_ = (const float4*)(pred + bb_ * 512);                 \
        if (bb_ + SUPER <= (long)B) {          /* fast path: full super */     \
            S##_q0 = gp_[lane];        S##_q1 = gp_[lane + 64];                \
            S##_q2 = gp_[lane + 128];  S##_q3 = gp_[lane + 192];               \
            S##_q4 = gp_[lane + 256];  S##_q5 = gp_[lane + 320];               \
            S##_q6 = gp_[lane + 384];  S##_q7 = gp_[lane + 448];               \
        } else {                                                               \
            const float4 z_ = make_float4(0.f, 0.f, 0.f, 0.f);                 \
            S##_q0 = S##_q1 = S##_q2 = S##_q3 = z_;                            \
            S##_q4 = S##_q5 = S##_q6 = S##_q7 = z_;                            \
            if (bb_ + 0 < (long)B) { S##_q0 = gp_[lane];       S##_q1 = gp_[lane + 64];  } \
            if (bb_ + 1 < (long)B) { S##_q2 = gp_[lane + 128]; S##_q3 = gp_[lane + 192]; } \
            if (bb_ + 2 < (long)B) { S##_q4 = gp_[lane + 256]; S##_q5 = gp_[lane + 320]; } \
            if (bb_ + 3 < (long)B) { S##_q6 = gp_[lane + 384]; S##_q7 = gp_[lane + 448]; } \
        }                                                                      \
    }

// Consume super g's LABELS only (short prefix wait), reset the dedup mask,
// and issue the 2-dwordx4 responsible-cell gather. Issued BEFORE the next
// super's prefetch so later waits never drain the stream.
#define GATHER_SUPER(S, g)                                                     \
    {                                                                          \
        if (lane < SUPER * 2) my_mask[lane] = 0u;                              \
        if (S##_ok) {                                                          \
            S##_cell = S##_rc.x * 8 + S##_rc.y;         /* 0..63 */            \
            const long bq_ = (long)(g) * SUPER + grp;                          \
            const float4* cp_ =                                                \
                (const float4*)(pred + (size_t)bq_ * 512 + (size_t)S##_cell * 8); \
            S##_c0 = cp_[0];                                                   \
            S##_c1 = cp_[1];                                                   \
        }                                                                      \
    }

// Full processing of super g: noobj sum (waits pred(g), prefix), dedup
// atomic, IoU + losses (waits gather(g), prefix; stream stays in flight).
#define PROC_SUPER(S)                                                          \
    {                                                                          \
        noobj_acc += S##_q0.w * S##_q0.w + S##_q1.w * S##_q1.w                 \
                   + S##_q2.w * S##_q2.w + S##_q3.w * S##_q3.w                 \
                   + S##_q4.w * S##_q4.w + S##_q5.w * S##_q5.w                 \
                   + S##_q6.w * S##_q6.w + S##_q7.w * S##_q7.w;                \
        if (S##_ok) {                                                          \
            const unsigned bit_ = 1u << (S##_cell & 31);                       \
            const unsigned old_ =                                              \
                atomicOr(&my_mask[grp * 2 + (S##_cell >> 5)], bit_);           \
            const float p0 = S##_c0.x, p1 = S##_c0.y, p2 = S##_c0.z, p3 = S##_c0.w; \
            const float p4 = S##_c1.x, p5 = S##_c1.y, p6 = S##_c1.z, p7 = S##_c1.w; \
            const float iou1 = bbox_iou(p0, p1, p2, S##_gx, S##_gy, S##_gr);   \
            const float iou2 = bbox_iou(p4, p5, p6, S##_gx, S##_gy, S##_gr);   \
            const bool  sw_ = iou2 > iou1;                                     \
            const float cx = sw_ ? p4 : p0;                                    \
            const float cy = sw_ ? p5 : p1;                                    \
            const float cr = sw_ ? p6 : p2;                                    \
            const float conf    = sw_ ? p7 : p3;                               \
            const float un_conf = sw_ ? p3 : p7;                               \
            const float bigger  = sw_ ? iou2 : iou1;                           \
            const float smaller = sw_ ? iou1 : iou2;                           \
            const float dx = cx - S##_gx, dy = cy - S##_gy, dr = cr - S##_gr;  \
            main_acc += LAMBDA_COORD * (dx * dx + dy * dy + dr * dr);          \
            const float d1 = bigger - conf;                                    \
            main_acc += d1 * d1;                                               \
            const float d2 = smaller - un_conf;                                \
            noobj_acc += d2 * d2;                                              \
            if ((old_ & bit_) == 0u)     /* owner: subtract labeled cell */    \
                noobj_acc -= (p3 * p3 + p7 * p7);                              \
        }                                                                      \
    }

__global__ __launch_bounds__(256, 4) void yolo_loss_kernel(
    const float* __restrict__ pred,
    const int*   __restrict__ label_rc,
    const float* __restrict__ label_box,
    float* __restrict__ partials,
    int B, int L)
{
    __shared__ unsigned cmask[WAVES_PER_BLOCK][SUPER * 2];   // 128 B
    __shared__ float    wsum[WAVES_PER_BLOCK];

    const int tid  = threadIdx.x;
    const int lane = tid & 63;
    const int wv   = tid >> 6;
    const int grp  = lane >> 4;     // which batch of the super
    const int lj   = lane & 15;     // label index within that batch

    unsigned* my_mask = cmask[wv];

    const long waves_tot = (long)gridDim.x * WAVES_PER_BLOCK;
    const long wgid      = (long)blockIdx.x * WAVES_PER_BLOCK + wv;
    const long nsup      = ((long)B + SUPER - 1) / SUPER;
    const long spw       = (nsup + waves_tot - 1) / waves_tot;
    const long g_begin   = wgid * spw;
    const long g_end     = (g_begin + spw < nsup) ? (g_begin + spw) : nsup;

    float main_acc  = 0.0f;  // lambda_coord * coord + d1^2
    float noobj_acc = 0.0f;  // sum w^2 - owner(p3^2+p7^2) + d2^2 (x lambda at end)

    DECL_SUPER(A)
    DECL_SUPER(B)

    long g = g_begin;
    if (g < g_end) {
        LOAD_SUPER(A, g);
        while (true) {
            GATHER_SUPER(A, g);                        // wait labels(A) only
            if (g + 1 < g_end) LOAD_SUPER(B, g + 1);   // prefetch next
            PROC_SUPER(A);                             // stream stays in flight
            ++g; if (g >= g_end) break;
            GATHER_SUPER(B, g);
            if (g + 1 < g_end) LOAD_SUPER(A, g + 1);
            PROC_SUPER(B);
            ++g; if (g >= g_end) break;
        }
    }

    // ---- wave + block reduction -> one partial per block ----
    float acc = main_acc + LAMBDA_NOOBJ * noobj_acc;
    #pragma unroll
    for (int off = 32; off > 0; off >>= 1)
        acc += __shfl_xor(acc, off);
    if (lane == 0) wsum[wv] = acc;
    __syncthreads();
    if (tid == 0)
        partials[blockIdx.x] = wsum[0] + wsum[1] + wsum[2] + wsum[3];
}

__global__ __launch_bounds__(256) void reduce_kernel(
    const float* __restrict__ partials, float* __restrict__ out,
    int n, float invB)
{
    float s = 0.0f;
    for (int i = threadIdx.x; i < n; i += 256)
        s += partials[i];
    #pragma unroll
    for (int off = 32; off > 0; off >>= 1)
        s += __shfl_xor(s, off);

    __shared__ float wsum[4];
    const int lane = threadIdx.x & 63, w = threadIdx.x >> 6;
    if (lane == 0) wsum[w] = s;
    __syncthreads();
    if (threadIdx.x == 0)
        out[0] = (wsum[0] + wsum[1] + wsum[2] + wsum[3]) * invB;
}

extern "C" void kernel_launch(void* const* d_in, const int* in_sizes, int n_in,
                              void* d_out, int out_size, void* d_ws, size_t ws_size,
                              hipStream_t stream) {
    const float* pred      = (const float*)d_in[0];
    const int*   label_rc  = (const int*)d_in[1];
    const float* label_box = (const float*)d_in[2];
    float*       out       = (float*)d_out;
    float*       partials  = (float*)d_ws;

    const int B = in_sizes[0] / 512;          // G*G*C = 8*8*8
    const int L = in_sizes[1] / (B * 2);      // labels per batch (16)
    const float invB = 1.0f / (float)B;

    yolo_loss_kernel<<<NBLOCKS, 256, 0, stream>>>(
        pred, label_rc, label_box, partials, B, L);

    reduce_kernel<<<1, 256, 0, stream>>>(partials, out, NBLOCKS, invB);
}

// Round 6
// 204.897 us; speedup vs baseline: 1.0227x; 1.0088x over previous
//
#include <hip/hip_runtime.h>

// YOLO-style loss on MI355X — round 10 (R9 retry: fix nt-load types).
// pred:      [B, 8, 8, 8] f32   (B = 65536)
// label_rc:  [B, L, 2]    i32   (L = 16)
// label_box: [B, L, 3]    f32
// out:       [1] f32 = (coord + cond) / B
//
// R10 = R9's non-temporal-load experiment, compile-fixed:
// __builtin_nontemporal_load requires scalar or NATIVE vector element types;
// HIP's float4/int2 (HIP_vector_type) are rejected. Use clang ext_vector
// types (same layout) and convert.
//
// Theory under test (unchanged): four structurally different kernels
// (R4/R6/R7/R8) all pin at yolo ~62.5 us (148.5 MB @ 2.4 TB/s effective)
// while each bench iteration's 512 MiB poison fill runs at 86% HBM peak.
// The fill leaves the 256 MiB LLC fully DIRTY; every yolo read miss then
// forces a dirty-victim writeback -> ~150 MB reads + ~250 MB inherited
// writebacks ~= 63 us regardless of kernel structure. nt (evict-first)
// reads make yolo's misses victimize its own clean lines instead ->
// writeback debt stays parked in LLC, re-dirtied in place by the next fill.
//
// Pipeline identical to R8 (counted-vmcnt discipline by issue order):
//   per super i: wait labels(i) -> issue gather(i) -> issue labels(i+1)
//   then pred(i+1) -> noobj waits pred(i) -> IoU waits gather(i);
//   the bulk pred stream never drains. Dedup: one ds_or_rtn per label.

static constexpr float LAMBDA_COORD = 5.0f;
static constexpr float LAMBDA_NOOBJ = 0.5f;
static constexpr float EPS_F = 1e-9f;

#define WAVES_PER_BLOCK 4
#define SUPER   4         // batches per super-iteration (one per 16-lane group)
#define NBLOCKS 1024      // 4096 waves; 4 blocks/CU resident; 4 supers/wave

typedef float nfloat4 __attribute__((ext_vector_type(4)));
typedef int   nint2   __attribute__((ext_vector_type(2)));

__device__ __forceinline__ float4 nt_ld4(const float4* p) {
    nfloat4 v = __builtin_nontemporal_load((const nfloat4*)p);
    return make_float4(v.x, v.y, v.z, v.w);
}
__device__ __forceinline__ int2 nt_ld2i(const int* p) {
    nint2 v = __builtin_nontemporal_load((const nint2*)p);
    return make_int2(v.x, v.y);
}
__device__ __forceinline__ float nt_ldf(const float* p) {
    return __builtin_nontemporal_load(p);
}

__device__ __forceinline__ float bbox_iou(float px, float py, float pr,
                                          float gx, float gy, float gr) {
    float l1 = px - pr, r1 = px + pr, t1 = py - pr, b1 = py + pr;
    float l2 = gx - gr, r2 = gx + gr, t2 = gy - gr, b2 = gy + gr;
    float iw = fmaxf(fminf(r1, r2) - fmaxf(l1, l2), 0.0f);
    float ih = fmaxf(fminf(b1, b2) - fmaxf(t1, t2), 0.0f);
    float inter = iw * ih;
    float a1 = (r1 - l1) * (b1 - t1);
    float a2 = (r2 - l2) * (b2 - t2);
    return inter / (a1 + a2 - inter + EPS_F);
}

// Per-super register state.
#define DECL_SUPER(S)                                                          \
    float4 S##_q0, S##_q1, S##_q2, S##_q3, S##_q4, S##_q5, S##_q6, S##_q7;     \
    int2   S##_rc   = make_int2(0, 0);                                         \
    float  S##_gx = 0.f, S##_gy = 0.f, S##_gr = 0.f;                           \
    int    S##_ok = 0, S##_cell = 0;                                           \
    float4 S##_c0 = make_float4(0.f, 0.f, 0.f, 0.f);                           \
    float4 S##_c1 = make_float4(0.f, 0.f, 0.f, 0.f);

// Issue super g's loads: labels FIRST (so next iteration's label wait is a
// short queue prefix), then the 8-dwordx4 pred stream. All non-temporal.
#define LOAD_SUPER(S, g)                                                       \
    {                                                                          \
        const long bb_ = (long)(g) * SUPER;                                    \
        const long bq_ = bb_ + grp;                                            \
        S##_ok = (bq_ < (long)B) && (lj < L);                                  \
        if (S##_ok) {                                                          \
            S##_rc = nt_ld2i(label_rc + ((size_t)bq_ * L + lj) * 2);           \
            const float* lb_ = label_box + ((size_t)bq_ * L + lj) * 3;         \
            S##_gx = nt_ldf(lb_ + 0);                                          \
            S##_gy = nt_ldf(lb_ + 1);                                          \
            S##_gr = nt_ldf(lb_ + 2);                                          \
        }                                                                      \
        const float4* gp_ = (const float4*)(pred + bb_ * 512);                 \
        if (bb_ + SUPER <= (long)B) {          /* fast path: full super */     \
            S##_q0 = nt_ld4(gp_ + lane);        S##_q1 = nt_ld4(gp_ + lane + 64);  \
            S##_q2 = nt_ld4(gp_ + lane + 128);  S##_q3 = nt_ld4(gp_ + lane + 192); \
            S##_q4 = nt_ld4(gp_ + lane + 256);  S##_q5 = nt_ld4(gp_ + lane + 320); \
            S##_q6 = nt_ld4(gp_ + lane + 384);  S##_q7 = nt_ld4(gp_ + lane + 448); \
        } else {                                                               \
            const float4 z_ = make_float4(0.f, 0.f, 0.f, 0.f);                 \
            S##_q0 = S##_q1 = S##_q2 = S##_q3 = z_;                            \
            S##_q4 = S##_q5 = S##_q6 = S##_q7 = z_;                            \
            if (bb_ + 0 < (long)B) { S##_q0 = nt_ld4(gp_ + lane);       S##_q1 = nt_ld4(gp_ + lane + 64);  } \
            if (bb_ + 1 < (long)B) { S##_q2 = nt_ld4(gp_ + lane + 128); S##_q3 = nt_ld4(gp_ + lane + 192); } \
            if (bb_ + 2 < (long)B) { S##_q4 = nt_ld4(gp_ + lane + 256); S##_q5 = nt_ld4(gp_ + lane + 320); } \
            if (bb_ + 3 < (long)B) { S##_q6 = nt_ld4(gp_ + lane + 384); S##_q7 = nt_ld4(gp_ + lane + 448); } \
        }                                                                      \
    }

// Consume super g's LABELS only (short prefix wait), reset the dedup mask,
// and issue the 2-dwordx4 responsible-cell gather (lines are cache-hot:
// streamed by this wave moments ago; nt = last use).
#define GATHER_SUPER(S, g)                                                     \
    {                                                                          \
        if (lane < SUPER * 2) my_mask[lane] = 0u;                              \
        if (S##_ok) {                                                          \
            S##_cell = S##_rc.x * 8 + S##_rc.y;         /* 0..63 */            \
            const long bq_ = (long)(g) * SUPER + grp;                          \
            const float4* cp_ =                                                \
                (const float4*)(pred + (size_t)bq_ * 512 + (size_t)S##_cell * 8); \
            S##_c0 = nt_ld4(cp_ + 0);                                          \
            S##_c1 = nt_ld4(cp_ + 1);                                          \
        }                                                                      \
    }

// Full processing of super g: noobj sum (waits pred(g), prefix), dedup
// atomic, IoU + losses (waits gather(g), prefix; stream stays in flight).
#define PROC_SUPER(S)                                                          \
    {                                                                          \
        noobj_acc += S##_q0.w * S##_q0.w + S##_q1.w * S##_q1.w                 \
                   + S##_q2.w * S##_q2.w + S##_q3.w * S##_q3.w                 \
                   + S##_q4.w * S##_q4.w + S##_q5.w * S##_q5.w                 \
                   + S##_q6.w * S##_q6.w + S##_q7.w * S##_q7.w;                \
        if (S##_ok) {                                                          \
            const unsigned bit_ = 1u << (S##_cell & 31);                       \
            const unsigned old_ =                                              \
                atomicOr(&my_mask[grp * 2 + (S##_cell >> 5)], bit_);           \
            const float p0 = S##_c0.x, p1 = S##_c0.y, p2 = S##_c0.z, p3 = S##_c0.w; \
            const float p4 = S##_c1.x, p5 = S##_c1.y, p6 = S##_c1.z, p7 = S##_c1.w; \
            const float iou1 = bbox_iou(p0, p1, p2, S##_gx, S##_gy, S##_gr);   \
            const float iou2 = bbox_iou(p4, p5, p6, S##_gx, S##_gy, S##_gr);   \
            const bool  sw_ = iou2 > iou1;                                     \
            const float cx = sw_ ? p4 : p0;                                    \
            const float cy = sw_ ? p5 : p1;                                    \
            const float cr = sw_ ? p6 : p2;                                    \
            const float conf    = sw_ ? p7 : p3;                               \
            const float un_conf = sw_ ? p3 : p7;                               \
            const float bigger  = sw_ ? iou2 : iou1;                           \
            const float smaller = sw_ ? iou1 : iou2;                           \
            const float dx = cx - S##_gx, dy = cy - S##_gy, dr = cr - S##_gr;  \
            main_acc += LAMBDA_COORD * (dx * dx + dy * dy + dr * dr);          \
            const float d1 = bigger - conf;                                    \
            main_acc += d1 * d1;                                               \
            const float d2 = smaller - un_conf;                                \
            noobj_acc += d2 * d2;                                              \
            if ((old_ & bit_) == 0u)     /* owner: subtract labeled cell */    \
                noobj_acc -= (p3 * p3 + p7 * p7);                              \
        }                                                                      \
    }

__global__ __launch_bounds__(256, 4) void yolo_loss_kernel(
    const float* __restrict__ pred,
    const int*   __restrict__ label_rc,
    const float* __restrict__ label_box,
    float* __restrict__ partials,
    int B, int L)
{
    __shared__ unsigned cmask[WAVES_PER_BLOCK][SUPER * 2];   // 128 B
    __shared__ float    wsum[WAVES_PER_BLOCK];

    const int tid  = threadIdx.x;
    const int lane = tid & 63;
    const int wv   = tid >> 6;
    const int grp  = lane >> 4;     // which batch of the super
    const int lj   = lane & 15;     // label index within that batch

    unsigned* my_mask = cmask[wv];

    const long waves_tot = (long)gridDim.x * WAVES_PER_BLOCK;
    const long wgid      = (long)blockIdx.x * WAVES_PER_BLOCK + wv;
    const long nsup      = ((long)B + SUPER - 1) / SUPER;
    const long spw       = (nsup + waves_tot - 1) / waves_tot;
    const long g_begin   = wgid * spw;
    const long g_end     = (g_begin + spw < nsup) ? (g_begin + spw) : nsup;

    float main_acc  = 0.0f;  // lambda_coord * coord + d1^2
    float noobj_acc = 0.0f;  // sum w^2 - owner(p3^2+p7^2) + d2^2 (x lambda at end)

    DECL_SUPER(A)
    DECL_SUPER(B)

    long g = g_begin;
    if (g < g_end) {
        LOAD_SUPER(A, g);
        while (true) {
            GATHER_SUPER(A, g);                        // wait labels(A) only
            if (g + 1 < g_end) LOAD_SUPER(B, g + 1);   // prefetch next
            PROC_SUPER(A);                             // stream stays in flight
            ++g; if (g >= g_end) break;
            GATHER_SUPER(B, g);
            if (g + 1 < g_end) LOAD_SUPER(A, g + 1);
            PROC_SUPER(B);
            ++g; if (g >= g_end) break;
        }
    }

    // ---- wave + block reduction -> one partial per block ----
    float acc = main_acc + LAMBDA_NOOBJ * noobj_acc;
    #pragma unroll
    for (int off = 32; off > 0; off >>= 1)
        acc += __shfl_xor(acc, off);
    if (lane == 0) wsum[wv] = acc;
    __syncthreads();
    if (tid == 0)
        partials[blockIdx.x] = wsum[0] + wsum[1] + wsum[2] + wsum[3];
}

__global__ __launch_bounds__(256) void reduce_kernel(
    const float* __restrict__ partials, float* __restrict__ out,
    int n, float invB)
{
    float s = 0.0f;
    for (int i = threadIdx.x; i < n; i += 256)
        s += partials[i];
    #pragma unroll
    for (int off = 32; off > 0; off >>= 1)
        s += __shfl_xor(s, off);

    __shared__ float wsum[4];
    const int lane = threadIdx.x & 63, w = threadIdx.x >> 6;
    if (lane == 0) wsum[w] = s;
    __syncthreads();
    if (threadIdx.x == 0)
        out[0] = (wsum[0] + wsum[1] + wsum[2] + wsum[3]) * invB;
}

extern "C" void kernel_launch(void* const* d_in, const int* in_sizes, int n_in,
                              void* d_out, int out_size, void* d_ws, size_t ws_size,
                              hipStream_t stream) {
    const float* pred      = (const float*)d_in[0];
    const int*   label_rc  = (const int*)d_in[1];
    const float* label_box = (const float*)d_in[2];
    float*       out       = (float*)d_out;
    float*       partials  = (float*)d_ws;

    const int B = in_sizes[0] / 512;          // G*G*C = 8*8*8
    const int L = in_sizes[1] / (B * 2);      // labels per batch (16)
    const float invB = 1.0f / (float)B;

    yolo_loss_kernel<<<NBLOCKS, 256, 0, stream>>>(
        pred, label_rc, label_box, partials, B, L);

    reduce_kernel<<<1, 256, 0, stream>>>(partials, out, NBLOCKS, invB);
}